// Round 2
// baseline (439.404 us; speedup 1.0000x reference)
//
#include <hip/hip_runtime.h>

#define DFEAT 128
#define HID 16

__device__ __forceinline__ float bf2f(unsigned v) { return __uint_as_float(v << 16); }
__device__ __forceinline__ unsigned short f2bf(float f) {
    unsigned u = __float_as_uint(f);
    return (unsigned short)((u + 0x7FFFu + ((u >> 16) & 1u)) >> 16);
}

// flags[0] = 1 if float tensors are bf16, 0 if f32
// flags[1] = 1 if edge_index is int64, 0 if int32
// Parallel: one wave, ballot-reduced (old single-thread version was ~190
// dependent global loads = tens of µs).
__global__ void k_detect(const unsigned short* __restrict__ x,
                         const int* __restrict__ ei,
                         int* __restrict__ flags) {
    const int lane = threadIdx.x;  // blockDim = 64
    unsigned short v = x[2 * lane];
    int e = (v >> 7) & 0xFF;
    bool okbf = (v == 0) || (e >= 110 && e <= 130);
    unsigned long long mbf = __ballot(okbf);
    bool z = (ei[2 * lane + 1] == 0);
    unsigned long long mz = __ballot(z);
    if (lane == 0) {
        flags[0] = (__popcll(mbf) >= 52) ? 1 : 0;
        flags[1] = (__popcll(mz) >= 60) ? 1 : 0;
    }
}

// p1 = x @ w1_rel, q1 = x @ w1_root   (16 nodes per block, 256 threads)
__global__ __launch_bounds__(256) void k_lin1(const void* __restrict__ xv,
                                              const void* __restrict__ wrel,
                                              const void* __restrict__ wroot,
                                              float* __restrict__ p1,
                                              float* __restrict__ q1,
                                              const int* __restrict__ flags,
                                              int N) {
    __shared__ float xs[16][DFEAT + 1];
    __shared__ float2 sw[DFEAT * HID];   // interleaved {rel, root}: 1 b64 read/k

    const int t = threadIdx.x;
    const int bf = flags[0];
    const int nb = blockIdx.x * 16;

    if (bf) {
        const unsigned short* a = (const unsigned short*)wrel;
        const unsigned short* b = (const unsigned short*)wroot;
        for (int r = t; r < DFEAT * HID; r += 256)
            sw[r] = make_float2(bf2f(a[r]), bf2f(b[r]));
    } else {
        const float* a = (const float*)wrel;
        const float* b = (const float*)wroot;
        for (int r = t; r < DFEAT * HID; r += 256)
            sw[r] = make_float2(a[r], b[r]);
    }

    {
        const int row = (t * 8) >> 7;
        const int col = (t * 8) & 127;
        const int n = nb + row;
        if (n < N) {
            if (bf) {
                const unsigned short* xp = (const unsigned short*)xv;
                uint4 v = *(const uint4*)(xp + (size_t)n * DFEAT + col);
                xs[row][col + 0] = bf2f(v.x & 0xFFFFu);
                xs[row][col + 1] = bf2f(v.x >> 16);
                xs[row][col + 2] = bf2f(v.y & 0xFFFFu);
                xs[row][col + 3] = bf2f(v.y >> 16);
                xs[row][col + 4] = bf2f(v.z & 0xFFFFu);
                xs[row][col + 5] = bf2f(v.z >> 16);
                xs[row][col + 6] = bf2f(v.w & 0xFFFFu);
                xs[row][col + 7] = bf2f(v.w >> 16);
            } else {
                const float* xp = (const float*)xv;
                const float4* s = (const float4*)(xp + (size_t)n * DFEAT + col);
                float4 v0 = s[0], v1 = s[1];
                xs[row][col + 0] = v0.x; xs[row][col + 1] = v0.y;
                xs[row][col + 2] = v0.z; xs[row][col + 3] = v0.w;
                xs[row][col + 4] = v1.x; xs[row][col + 5] = v1.y;
                xs[row][col + 6] = v1.z; xs[row][col + 7] = v1.w;
            }
        }
    }
    __syncthreads();

    const int i = t >> 4;
    const int j = t & 15;
    float accp = 0.f, accq = 0.f;
#pragma unroll 8
    for (int k = 0; k < DFEAT; k++) {
        float xvv = xs[i][k];
        float2 w = sw[k * HID + j];
        accp += xvv * w.x;
        accq += xvv * w.y;
    }
    const int n2 = nb + i;
    if (n2 < N) {
        p1[(size_t)n2 * HID + j] = accp;
        q1[(size_t)n2 * HID + j] = accq;
    }
}

// ---- CSR build: counting sort of edges by dst ----

__global__ __launch_bounds__(256) void k_hist(const int* __restrict__ ei,
                                              int* __restrict__ counts,
                                              const int* __restrict__ flags,
                                              int E) {
    const int e = blockIdx.x * 256 + threadIdx.x;
    if (e >= E) return;
    int dst = flags[1] ? ei[2 * ((size_t)E + e)] : ei[(size_t)E + e];
    atomicAdd(counts + dst, 1);
}

__global__ __launch_bounds__(256) void k_scan_blocks(const int* __restrict__ counts,
                                                     int* __restrict__ blocksums,
                                                     int N) {
    const int t = threadIdx.x;
    const int i = blockIdx.x * 256 + t;
    int c = (i < N) ? counts[i] : 0;
#pragma unroll
    for (int off = 32; off > 0; off >>= 1) c += __shfl_down(c, off, 64);
    __shared__ int ws[4];
    if ((t & 63) == 0) ws[t >> 6] = c;
    __syncthreads();
    if (t == 0) blocksums[blockIdx.x] = ws[0] + ws[1] + ws[2] + ws[3];
}

__global__ __launch_bounds__(512) void k_scan_top(const int* __restrict__ blocksums,
                                                  int* __restrict__ blockoffs,
                                                  int NB) {
    __shared__ int s[512];
    const int t = threadIdx.x;
    int own = (t < NB) ? blocksums[t] : 0;
    s[t] = own;
    __syncthreads();
    for (int off = 1; off < 512; off <<= 1) {
        int v = (t >= off) ? s[t - off] : 0;
        __syncthreads();
        s[t] += v;
        __syncthreads();
    }
    if (t < NB) blockoffs[t] = s[t] - own;  // exclusive
}

__global__ __launch_bounds__(256) void k_scan_final(const int* __restrict__ counts,
                                                    const int* __restrict__ blockoffs,
                                                    int* __restrict__ offsets,
                                                    int* __restrict__ cursor,
                                                    int N, int E) {
    __shared__ int s[256];
    const int t = threadIdx.x;
    const int i = blockIdx.x * 256 + t;
    int c = (i < N) ? counts[i] : 0;
    s[t] = c;
    __syncthreads();
    for (int off = 1; off < 256; off <<= 1) {
        int v = (t >= off) ? s[t - off] : 0;
        __syncthreads();
        s[t] += v;
        __syncthreads();
    }
    int pos = blockoffs[blockIdx.x] + s[t] - c;  // exclusive
    if (i < N) { offsets[i] = pos; cursor[i] = pos; }
    if (blockIdx.x == 0 && t == 0) offsets[N] = E;
}

__global__ __launch_bounds__(256) void k_bin(const int* __restrict__ ei,
                                             int* __restrict__ cursor,
                                             int* __restrict__ sorted_src,
                                             const int* __restrict__ flags,
                                             int E) {
    const int e = blockIdx.x * 256 + threadIdx.x;
    if (e >= E) return;
    int src, dst;
    if (flags[1]) { src = ei[2 * (size_t)e]; dst = ei[2 * ((size_t)E + e)]; }
    else          { src = ei[e];             dst = ei[(size_t)E + e]; }
    int pos = atomicAdd(cursor + dst, 1);
    sorted_src[pos] = src;
}

// ---- Layer 1: agg = sum_{src->n} p1[src]; h=relu(agg+q1+b1); p2=h@w2rel; q2=h@w2root
// One thread per (node, channel); 16 nodes per 256-thread block; matmul via
// width-16 shuffles (each quad of 16 lanes holds one node's h vector).
__global__ __launch_bounds__(256) void k_agg1(const int* __restrict__ offsets,
                                              const int* __restrict__ sorted_src,
                                              const float* __restrict__ p1,
                                              const float* __restrict__ q1,
                                              const void* __restrict__ b1,
                                              const void* __restrict__ w2rel,
                                              const void* __restrict__ w2root,
                                              float* __restrict__ p2,
                                              float* __restrict__ q2,
                                              const int* __restrict__ flags,
                                              int N) {
    __shared__ float2 sw[HID * HID];
    __shared__ float sb[HID];
    const int t = threadIdx.x;
    const int bf = flags[0];
    if (bf) {
        const unsigned short* a = (const unsigned short*)w2rel;
        const unsigned short* b = (const unsigned short*)w2root;
        sw[t] = make_float2(bf2f(a[t]), bf2f(b[t]));
        if (t < HID) sb[t] = bf2f(((const unsigned short*)b1)[t]);
    } else {
        sw[t] = make_float2(((const float*)w2rel)[t], ((const float*)w2root)[t]);
        if (t < HID) sb[t] = ((const float*)b1)[t];
    }
    __syncthreads();

    const int n = blockIdx.x * 16 + (t >> 4);
    const int j = t & 15;
    if (n >= N) return;

    const int beg = offsets[n], end = offsets[n + 1];
    float acc = 0.f;
    for (int e = beg; e < end; e++) {
        int s = sorted_src[e];                 // broadcast within quad (L1)
        acc += p1[(size_t)s * HID + j];        // 64 B coalesced per quad
    }
    float h = fmaxf(acc + q1[(size_t)n * HID + j] + sb[j], 0.f);

    float sp = 0.f, sq = 0.f;
#pragma unroll
    for (int k = 0; k < HID; k++) {
        float hk = __shfl(h, k, 16);
        float2 w = sw[k * HID + j];
        sp += hk * w.x;
        sq += hk * w.y;
    }
    p2[(size_t)n * HID + j] = sp;
    q2[(size_t)n * HID + j] = sq;
}

// ---- Layer 2: agg2 = sum p2[src]; o = agg2+q2+b2; out = log_softmax(o)
__global__ __launch_bounds__(256) void k_agg2(const int* __restrict__ offsets,
                                              const int* __restrict__ sorted_src,
                                              const float* __restrict__ p2,
                                              const float* __restrict__ q2,
                                              const void* __restrict__ b2,
                                              void* __restrict__ out,
                                              const int* __restrict__ flags,
                                              int N) {
    __shared__ float sb[HID];
    const int t = threadIdx.x;
    const int bf = flags[0];
    if (t < HID) sb[t] = bf ? bf2f(((const unsigned short*)b2)[t]) : ((const float*)b2)[t];
    __syncthreads();

    const int n = blockIdx.x * 16 + (t >> 4);
    const int j = t & 15;
    if (n >= N) return;

    const int beg = offsets[n], end = offsets[n + 1];
    float acc = 0.f;
    for (int e = beg; e < end; e++) {
        int s = sorted_src[e];
        acc += p2[(size_t)s * HID + j];
    }
    float o = acc + q2[(size_t)n * HID + j] + sb[j];

    float m = o;
#pragma unroll
    for (int mask = 1; mask < HID; mask <<= 1) m = fmaxf(m, __shfl_xor(m, mask, 16));
    float s = __expf(o - m);
#pragma unroll
    for (int mask = 1; mask < HID; mask <<= 1) s += __shfl_xor(s, mask, 16);
    const float r = o - (m + __logf(s));

    if (bf) ((unsigned short*)out)[(size_t)n * HID + j] = f2bf(r);
    else    ((float*)out)[(size_t)n * HID + j] = r;
}

extern "C" void kernel_launch(void* const* d_in, const int* in_sizes, int n_in,
                              void* d_out, int out_size, void* d_ws, size_t ws_size,
                              hipStream_t stream) {
    const void* x       = d_in[0];
    const int*  ei      = (const int*)d_in[1];
    const void* w1_rel  = d_in[2];
    const void* w1_root = d_in[3];
    const void* b1      = d_in[4];
    const void* w2_rel  = d_in[5];
    const void* w2_root = d_in[6];
    const void* b2      = d_in[7];

    const int N = in_sizes[0] / DFEAT;   // 100000
    const int E = in_sizes[1] / 2;       // 1600000
    const int NB = (N + 255) / 256;      // 391 (<= 512 required by k_scan_top)

    float* ws   = (float*)d_ws;
    float* p1   = ws;
    float* q1   = p1 + (size_t)N * HID;
    float* p2   = q1 + (size_t)N * HID;
    float* q2   = p2 + (size_t)N * HID;
    int* counts    = (int*)(q2 + (size_t)N * HID);
    int* offsets   = counts + N;          // N+1
    int* cursor    = offsets + N + 1;
    int* blocksums = cursor + N;          // 512
    int* blockoffs = blocksums + 512;     // 512
    int* sorted_src= blockoffs + 512;     // E
    int* flags     = sorted_src + E;      // 2

    k_detect<<<1, 64, 0, stream>>>((const unsigned short*)x, ei, flags);
    hipMemsetAsync(counts, 0, (size_t)N * sizeof(int), stream);

    const int eb = (E + 255) / 256;
    k_hist<<<eb, 256, 0, stream>>>(ei, counts, flags, E);
    k_scan_blocks<<<NB, 256, 0, stream>>>(counts, blocksums, N);
    k_scan_top<<<1, 512, 0, stream>>>(blocksums, blockoffs, NB);
    k_scan_final<<<NB, 256, 0, stream>>>(counts, blockoffs, offsets, cursor, N, E);
    k_bin<<<eb, 256, 0, stream>>>(ei, cursor, sorted_src, flags, E);

    k_lin1<<<(N + 15) / 16, 256, 0, stream>>>(x, w1_rel, w1_root, p1, q1, flags, N);

    const int nb16 = (N + 15) / 16;
    k_agg1<<<nb16, 256, 0, stream>>>(offsets, sorted_src, p1, q1, b1, w2_rel, w2_root,
                                     p2, q2, flags, N);
    k_agg2<<<nb16, 256, 0, stream>>>(offsets, sorted_src, p2, q2, b2, d_out, flags, N);
}